// Round 1
// baseline (1581.480 us; speedup 1.0000x reference)
//
#include <hip/hip_runtime.h>
#include <math.h>

#define D_INN 256
#define D_HID 64
#define DTR 16
#define D_MEMM 128
#define BB 2
#define LL 2048
#define NROWS (BB*LL)   // 4096
#define NPROJ 736
#define NTOT 864        // 736 proj cols + 128 Q cols

// ---------------- Kernel 1: proj = x @ [W_xproj | W_Q] (+b_Q on Q cols) ----------------
__global__ __launch_bounds__(256) void k_gemm(const float* __restrict__ x,
        const float* __restrict__ Wx, const float* __restrict__ Wq,
        const float* __restrict__ bq, float* __restrict__ proj) {
    __shared__ float As[16][64];
    __shared__ float Bs[16][64];
    int tid = threadIdx.x;
    int tx = tid & 15, ty = tid >> 4;
    int row0 = blockIdx.y * 64;
    int col0 = blockIdx.x * 64;
    float acc[4][4] = {};
    for (int k0 = 0; k0 < D_INN; k0 += 16) {
        #pragma unroll
        for (int i = 0; i < 4; i++) {
            int idx = tid + i * 256;
            int kk = idx & 15, m = idx >> 4;
            As[kk][m] = x[(size_t)(row0 + m) * D_INN + k0 + kk];
        }
        #pragma unroll
        for (int i = 0; i < 4; i++) {
            int idx = tid + i * 256;
            int n = idx & 63, kk = idx >> 6;
            int col = col0 + n;
            float v = 0.f;
            if (col < NPROJ) v = Wx[(size_t)(k0 + kk) * NPROJ + col];
            else if (col < NTOT) v = Wq[(size_t)(k0 + kk) * D_MEMM + (col - NPROJ)];
            Bs[kk][n] = v;
        }
        __syncthreads();
        #pragma unroll
        for (int kk = 0; kk < 16; kk++) {
            float4 a4 = *(const float4*)&As[kk][ty * 4];
            float4 b4 = *(const float4*)&Bs[kk][tx * 4];
            float av[4] = {a4.x, a4.y, a4.z, a4.w};
            float bv[4] = {b4.x, b4.y, b4.z, b4.w};
            #pragma unroll
            for (int i = 0; i < 4; i++)
                #pragma unroll
                for (int j = 0; j < 4; j++)
                    acc[i][j] += av[i] * bv[j];
        }
        __syncthreads();
    }
    #pragma unroll
    for (int i = 0; i < 4; i++) {
        int row = row0 + ty * 4 + i;
        #pragma unroll
        for (int j = 0; j < 4; j++) {
            int col = col0 + tx * 4 + j;
            if (col < NTOT) {
                float v = acc[i][j];
                if (col >= NPROJ) v += bq[col - NPROJ];
                proj[(size_t)row * NTOT + col] = v;
            }
        }
    }
}

// ---------------- Kernel 2: delta / delta_l = softplus(dt @ W + b) ----------------
__global__ __launch_bounds__(256) void k_delta(const float* __restrict__ proj,
        const float* __restrict__ Wdt, const float* __restrict__ bdt,
        const float* __restrict__ Wdtl, const float* __restrict__ bdtl,
        float* __restrict__ delta, float* __restrict__ deltal) {
    __shared__ float sdt[16], sdtl[16];
    int row = blockIdx.x;
    int t = threadIdx.x;
    if (t < 16) sdt[t] = proj[(size_t)row * NTOT + 704 + t];
    else if (t < 32) sdtl[t - 16] = proj[(size_t)row * NTOT + 720 + (t - 16)];
    __syncthreads();
    float a1 = bdt[t], a2 = bdtl[t];
    #pragma unroll
    for (int r = 0; r < DTR; r++) {
        a1 += sdt[r] * Wdt[r * D_INN + t];
        a2 += sdtl[r] * Wdtl[r * D_INN + t];
    }
    delta[(size_t)row * D_INN + t]  = (a1 > 20.f) ? a1 : log1pf(expf(a1));
    deltal[(size_t)row * D_INN + t] = (a2 > 20.f) ? a2 : log1pf(expf(a2));
}

// ---------------- Kernel 3: the two selective scans ----------------
// grid (64 d-tiles, 2 batch, 2 scans); block 256 = 4 waves; wave w owns d = bx*4+w, lane = n.
__global__ __launch_bounds__(256) void k_scan(const float* __restrict__ x,
        const float* __restrict__ proj, const float* __restrict__ A,
        const float* __restrict__ Dp, const float* __restrict__ delta,
        const float* __restrict__ deltal,
        float* __restrict__ y, float* __restrict__ mem) {
    __shared__ float buf[4][16][65];
    int w = threadIdx.x >> 6, n = threadIdx.x & 63;
    int b = blockIdx.y, scan = blockIdx.z;
    int d = blockIdx.x * 4 + w;
    const float* dptr = (scan == 0 ? delta : deltal) + ((size_t)b * LL) * D_INN + d;
    const float* brow = proj + ((size_t)b * LL) * NTOT + (scan == 0 ? 0 : 64) + n;
    const float* crow = proj + ((size_t)b * LL) * NTOT + 128 + n;
    const float* uptr = x + ((size_t)b * LL) * D_INN + d;
    float Aln = A[d * D_HID + n] * 1.44269504f;
    float s = 0.f;
    for (int c = 0; c < LL / 16; c++) {
        #pragma unroll
        for (int li = 0; li < 16; li++) {
            int l = c * 16 + li;
            float dv = dptr[(size_t)l * D_INN];
            float uv = uptr[(size_t)l * D_INN];
            float Bv = brow[(size_t)l * NTOT];
            float dA = exp2f(dv * Aln);
            s = dA * s + (dv * uv) * Bv;
            float pv = (scan == 0) ? s * crow[(size_t)l * NTOT] : s;
            buf[w][li][n] = pv;
        }
        __syncthreads();
        int p = threadIdx.x >> 2, sub = threadIdx.x & 3;
        int rw = p >> 4, rli = p & 15;
        if (scan == 0 || rli == 0) {   // group-of-4 uniform guard
            float acc = 0.f;
            #pragma unroll
            for (int j = 0; j < 16; j++) acc += buf[rw][rli][sub * 16 + j];
            acc += __shfl_xor(acc, 1);
            acc += __shfl_xor(acc, 2);
            if (sub == 0) {
                int l = c * 16 + rli;
                int dd = blockIdx.x * 4 + rw;
                size_t row = (size_t)b * LL + l;
                if (scan == 0) {
                    y[row * D_INN + dd] = acc + x[row * D_INN + dd] * Dp[dd];
                } else {
                    mem[((size_t)b * 128 + (l >> 4)) * D_INN + dd] = acc;
                }
            }
        }
        __syncthreads();
    }
}

// ---------------- Kernel 4: K, V = memory @ W_K/V + b ----------------
__global__ __launch_bounds__(128) void k_kv(const float* __restrict__ mem,
        const float* __restrict__ Wk, const float* __restrict__ bk,
        const float* __restrict__ Wv, const float* __restrict__ bv,
        float* __restrict__ K, float* __restrict__ V) {
    __shared__ float mrow[256];
    int k = blockIdx.x, b = blockIdx.y;
    int t = threadIdx.x;
    const float* mr = mem + ((size_t)b * 128 + k) * D_INN;
    mrow[t] = mr[t];
    mrow[t + 128] = mr[t + 128];
    __syncthreads();
    float aK = bk[t], aV = bv[t];
    for (int dd = 0; dd < D_INN; dd++) {
        float m = mrow[dd];
        aK += m * Wk[dd * D_MEMM + t];
        aV += m * Wv[dd * D_MEMM + t];
    }
    K[((size_t)b * 128 + k) * D_MEMM + t] = aK;
    V[((size_t)b * 128 + k) * D_MEMM + t] = aV;
}

// ---------------- Kernel 5: attention + epilogue ----------------
__global__ __launch_bounds__(256) void k_attn(const float* __restrict__ x,
        const float* __restrict__ proj, const float* __restrict__ y,
        const float* __restrict__ K, const float* __restrict__ V,
        const float* __restrict__ Wo, const float* __restrict__ bo,
        float* __restrict__ out) {
    __shared__ float q[128], sc[128], att[128];
    __shared__ float red[4];
    int l = blockIdx.x, b = blockIdx.y;
    size_t row = (size_t)b * LL + l;
    int t = threadIdx.x;
    if (t < 128) q[t] = proj[row * NTOT + NPROJ + t];
    __syncthreads();
    float scv = 0.f;
    if (t < 128) {
        const float* Kr = K + ((size_t)b * 128 + t) * D_MEMM;
        float a = 0.f;
        for (int m = 0; m < 128; m++) a += q[m] * Kr[m];
        scv = a * 0.125f;   // 1/sqrt(D_HIDDEN=64)
    }
    float v = (t < 128) ? scv : -3.4e38f;
    #pragma unroll
    for (int o = 1; o < 64; o <<= 1) v = fmaxf(v, __shfl_xor(v, o));
    if ((t & 63) == 0 && t < 128) red[t >> 6] = v;
    __syncthreads();
    float mx = fmaxf(red[0], red[1]);
    float ex = 0.f;
    if (t < 128) { ex = expf(scv - mx); sc[t] = ex; }
    float sv = (t < 128) ? ex : 0.f;
    #pragma unroll
    for (int o = 1; o < 64; o <<= 1) sv += __shfl_xor(sv, o);
    if ((t & 63) == 0 && t < 128) red[2 + (t >> 6)] = sv;
    __syncthreads();
    float denom = red[2] + red[3];
    if (t < 128) {
        const float* Vb = V + (size_t)b * 128 * D_MEMM;
        float a = 0.f;
        for (int k = 0; k < 128; k++) a += sc[k] * Vb[k * D_MEMM + t];
        att[t] = a / denom;
    }
    __syncthreads();
    float acc = bo[t];
    for (int m = 0; m < 128; m++) acc += att[m] * Wo[m * D_INN + t];
    float Ev = proj[row * NTOT + 192 + t];
    float Fv = proj[row * NTOT + 448 + t];
    out[row * D_INN + t] = y[row * D_INN + t] + acc * Ev + x[row * D_INN + t] * Fv;
}

extern "C" void kernel_launch(void* const* d_in, const int* in_sizes, int n_in,
                              void* d_out, int out_size, void* d_ws, size_t ws_size,
                              hipStream_t stream) {
    const float* x    = (const float*)d_in[0];
    const float* Wx   = (const float*)d_in[1];
    const float* Wdt  = (const float*)d_in[2];
    const float* bdt  = (const float*)d_in[3];
    const float* Wdtl = (const float*)d_in[4];
    const float* bdtl = (const float*)d_in[5];
    const float* A    = (const float*)d_in[6];
    const float* Dp   = (const float*)d_in[7];
    const float* Wq   = (const float*)d_in[8];
    const float* bq   = (const float*)d_in[9];
    const float* Wk   = (const float*)d_in[10];
    const float* bk   = (const float*)d_in[11];
    const float* Wv   = (const float*)d_in[12];
    const float* bv   = (const float*)d_in[13];
    const float* Wo   = (const float*)d_in[14];
    const float* bo   = (const float*)d_in[15];
    float* out = (float*)d_out;
    float* ws = (float*)d_ws;

    float* proj   = ws;                                    // 4096*864
    float* delta  = proj + (size_t)NROWS * NTOT;           // 4096*256
    float* deltal = delta + (size_t)NROWS * D_INN;         // 4096*256
    float* yb     = deltal + (size_t)NROWS * D_INN;        // 4096*256
    float* mem    = yb + (size_t)NROWS * D_INN;            // 2*128*256
    float* Kb     = mem + (size_t)BB * 128 * D_INN;        // 2*128*128
    float* Vb     = Kb + (size_t)BB * 128 * D_MEMM;        // 2*128*128

    hipLaunchKernelGGL(k_gemm, dim3(14, 64), dim3(256), 0, stream, x, Wx, Wq, bq, proj);
    hipLaunchKernelGGL(k_delta, dim3(NROWS), dim3(256), 0, stream,
                       proj, Wdt, bdt, Wdtl, bdtl, delta, deltal);
    hipLaunchKernelGGL(k_scan, dim3(64, 2, 2), dim3(256), 0, stream,
                       x, proj, A, Dp, delta, deltal, yb, mem);
    hipLaunchKernelGGL(k_kv, dim3(128, 2), dim3(128), 0, stream,
                       mem, Wk, bk, Wv, bv, Kb, Vb);
    hipLaunchKernelGGL(k_attn, dim3(LL, 2), dim3(256), 0, stream,
                       x, proj, yb, Kb, Vb, Wo, bo, out);
}

// Round 2
// 406.440 us; speedup vs baseline: 3.8911x; 3.8911x over previous
//
#include <hip/hip_runtime.h>
#include <math.h>

#define D_INN 256
#define D_HID 64
#define DTR 16
#define D_MEMM 128
#define BB 2
#define LL 2048
#define NROWS (BB*LL)   // 4096
#define NPROJ 736
#define NTOT 864        // 736 proj cols + 128 Q cols

// ---------------- Kernel 1: proj = x @ [W_xproj | W_Q] (+b_Q on Q cols) ----------------
__global__ __launch_bounds__(256) void k_gemm(const float* __restrict__ x,
        const float* __restrict__ Wx, const float* __restrict__ Wq,
        const float* __restrict__ bq, float* __restrict__ proj) {
    __shared__ float As[16][64];
    __shared__ float Bs[16][64];
    int tid = threadIdx.x;
    int tx = tid & 15, ty = tid >> 4;
    int row0 = blockIdx.y * 64;
    int col0 = blockIdx.x * 64;
    float acc[4][4] = {};
    for (int k0 = 0; k0 < D_INN; k0 += 16) {
        #pragma unroll
        for (int i = 0; i < 4; i++) {
            int idx = tid + i * 256;
            int kk = idx & 15, m = idx >> 4;
            As[kk][m] = x[(size_t)(row0 + m) * D_INN + k0 + kk];
        }
        #pragma unroll
        for (int i = 0; i < 4; i++) {
            int idx = tid + i * 256;
            int n = idx & 63, kk = idx >> 6;
            int col = col0 + n;
            float v = 0.f;
            if (col < NPROJ) v = Wx[(size_t)(k0 + kk) * NPROJ + col];
            else if (col < NTOT) v = Wq[(size_t)(k0 + kk) * D_MEMM + (col - NPROJ)];
            Bs[kk][n] = v;
        }
        __syncthreads();
        #pragma unroll
        for (int kk = 0; kk < 16; kk++) {
            float4 a4 = *(const float4*)&As[kk][ty * 4];
            float4 b4 = *(const float4*)&Bs[kk][tx * 4];
            float av[4] = {a4.x, a4.y, a4.z, a4.w};
            float bv[4] = {b4.x, b4.y, b4.z, b4.w};
            #pragma unroll
            for (int i = 0; i < 4; i++)
                #pragma unroll
                for (int j = 0; j < 4; j++)
                    acc[i][j] += av[i] * bv[j];
        }
        __syncthreads();
    }
    #pragma unroll
    for (int i = 0; i < 4; i++) {
        int row = row0 + ty * 4 + i;
        #pragma unroll
        for (int j = 0; j < 4; j++) {
            int col = col0 + tx * 4 + j;
            if (col < NTOT) {
                float v = acc[i][j];
                if (col >= NPROJ) v += bq[col - NPROJ];
                proj[(size_t)row * NTOT + col] = v;
            }
        }
    }
}

// ---------------- Kernel 2: delta / delta_l = softplus(dt @ W + b) ----------------
__global__ __launch_bounds__(256) void k_delta(const float* __restrict__ proj,
        const float* __restrict__ Wdt, const float* __restrict__ bdt,
        const float* __restrict__ Wdtl, const float* __restrict__ bdtl,
        float* __restrict__ delta, float* __restrict__ deltal) {
    __shared__ float sdt[16], sdtl[16];
    int row = blockIdx.x;
    int t = threadIdx.x;
    if (t < 16) sdt[t] = proj[(size_t)row * NTOT + 704 + t];
    else if (t < 32) sdtl[t - 16] = proj[(size_t)row * NTOT + 720 + (t - 16)];
    __syncthreads();
    float a1 = bdt[t], a2 = bdtl[t];
    #pragma unroll
    for (int r = 0; r < DTR; r++) {
        a1 += sdt[r] * Wdt[r * D_INN + t];
        a2 += sdtl[r] * Wdtl[r * D_INN + t];
    }
    delta[(size_t)row * D_INN + t]  = (a1 > 20.f) ? a1 : log1pf(expf(a1));
    deltal[(size_t)row * D_INN + t] = (a2 > 20.f) ? a2 : log1pf(expf(a2));
}

// ---------------- Kernel 3: the two selective scans (LDS double-buffered) ----------------
// grid (64, 2, 2); block 256 = 4 waves; wave w owns d = bx*4+w, lane = n in [0,64).
// Per 16-step chunk: stage B/C tiles + delta/x rows into LDS for chunk c+1 while
// computing chunk c from LDS. y-reduction deferred one chunk (double-buffered rbuf).
__global__ __launch_bounds__(256) void k_scan(const float* __restrict__ x,
        const float* __restrict__ proj, const float* __restrict__ A,
        const float* __restrict__ Dp, const float* __restrict__ delta,
        const float* __restrict__ deltal,
        float* __restrict__ y, float* __restrict__ mem) {
    __shared__ float Bs[2][16][64];
    __shared__ float Cs[2][16][64];
    __shared__ float dus[2][16][8];     // [li][0..3]=delta d0..d0+3, [4..7]=x d0..d0+3
    __shared__ float rbuf[2][4][16][65];

    const int t = threadIdx.x;
    const int w = t >> 6, n = t & 63;
    const int b = blockIdx.y, scan = blockIdx.z;
    const int d0 = blockIdx.x * 4;
    const int d = d0 + w;
    const size_t rowbase = (size_t)b * LL;
    const float* dsel = (scan == 0 ? delta : deltal);
    const int cB = (scan == 0) ? 0 : 64;

    const float Aln = A[d * D_HID + n] * 1.44269504f;

    // reduce-role mapping (2-way LDS conflicts only)
    const int rp = t >> 2, rsub = t & 3;
    const int rw = rp >> 4, rli = rp & 15;
    const float Dpv = Dp[d0 + rw];

    // loader roles for B/C tiles: 16 rows x 64 cols, float4 per thread
    const int lli = t >> 4, lc4 = (t & 15) * 4;

    float4 nB = {}, nC = {}, nDU = {};

    // ---- prologue: load chunk 0 ----
    {
        size_t row = rowbase + lli;
        nB = *(const float4*)&proj[row * NTOT + cB + lc4];
        if (scan == 0) nC = *(const float4*)&proj[row * NTOT + 128 + lc4];
        if (t < 16) nDU = *(const float4*)&dsel[(rowbase + t) * D_INN + d0];
        else if (t < 32) nDU = *(const float4*)&x[(rowbase + (t - 16)) * D_INN + d0];
    }
    *(float4*)&Bs[0][lli][lc4] = nB;
    if (scan == 0) *(float4*)&Cs[0][lli][lc4] = nC;
    if (t < 16) *(float4*)&dus[0][t][0] = nDU;
    else if (t < 32) *(float4*)&dus[0][t - 16][4] = nDU;
    __syncthreads();

    float s = 0.f;
    for (int c = 0; c < LL / 16; ++c) {
        const int cur = c & 1;
        const bool hn = (c + 1 < LL / 16);

        // issue global loads for chunk c+1 (no wait yet)
        if (hn) {
            int l0n = (c + 1) * 16;
            size_t row = rowbase + l0n + lli;
            nB = *(const float4*)&proj[row * NTOT + cB + lc4];
            if (scan == 0) nC = *(const float4*)&proj[row * NTOT + 128 + lc4];
            if (t < 16) nDU = *(const float4*)&dsel[(rowbase + l0n + t) * D_INN + d0];
            else if (t < 32) nDU = *(const float4*)&x[(rowbase + l0n + (t - 16)) * D_INN + d0];
        }

        // deferred y-reduction of chunk c-1 (reads rbuf[cur^1], safe vs compute below)
        if (scan == 0 && c > 0) {
            const int pc = cur ^ 1;
            float acc = 0.f;
            #pragma unroll
            for (int j = 0; j < 16; ++j) acc += rbuf[pc][rw][rli][rsub * 16 + j];
            acc += __shfl_xor(acc, 1);
            acc += __shfl_xor(acc, 2);
            if (rsub == 0) {
                size_t row = rowbase + (size_t)(c - 1) * 16 + rli;
                float xv = x[row * D_INN + d0 + rw];
                y[row * D_INN + d0 + rw] = acc + xv * Dpv;
            }
        }

        // compute 16 serial steps from LDS[cur]
        float pv[16];
        #pragma unroll
        for (int li = 0; li < 16; ++li) {
            float dv = dus[cur][li][w];
            float uv = dus[cur][li][4 + w];
            float Bv = Bs[cur][li][n];
            float dA = exp2f(dv * Aln);
            s = fmaf(dA, s, (dv * uv) * Bv);
            pv[li] = (scan == 0) ? s * Cs[cur][li][n] : s;
        }
        if (scan == 0) {
            #pragma unroll
            for (int li = 0; li < 16; ++li) rbuf[cur][w][li][n] = pv[li];
        } else {
            // memory = y_local[:, ::16]: only li==0 of each chunk contributes
            float v = pv[0];
            #pragma unroll
            for (int off = 32; off >= 1; off >>= 1) v += __shfl_xor(v, off);
            if (n == 0) mem[((size_t)b * 128 + c) * D_INN + d] = v;
        }

        // commit chunk c+1 into LDS[cur^1] (waits on the global loads here)
        if (hn) {
            const int nxt = cur ^ 1;
            *(float4*)&Bs[nxt][lli][lc4] = nB;
            if (scan == 0) *(float4*)&Cs[nxt][lli][lc4] = nC;
            if (t < 16) *(float4*)&dus[nxt][t][0] = nDU;
            else if (t < 32) *(float4*)&dus[nxt][t - 16][4] = nDU;
        }
        __syncthreads();
    }

    // epilogue: reduce last chunk (c = 127)
    if (scan == 0) {
        const int pc = (LL / 16 - 1) & 1;
        float acc = 0.f;
        #pragma unroll
        for (int j = 0; j < 16; ++j) acc += rbuf[pc][rw][rli][rsub * 16 + j];
        acc += __shfl_xor(acc, 1);
        acc += __shfl_xor(acc, 2);
        if (rsub == 0) {
            size_t row = rowbase + (size_t)(LL / 16 - 1) * 16 + rli;
            float xv = x[row * D_INN + d0 + rw];
            y[row * D_INN + d0 + rw] = acc + xv * Dpv;
        }
    }
}

// ---------------- Kernel 4: K, V = memory @ W_K/V + b ----------------
__global__ __launch_bounds__(128) void k_kv(const float* __restrict__ mem,
        const float* __restrict__ Wk, const float* __restrict__ bk,
        const float* __restrict__ Wv, const float* __restrict__ bv,
        float* __restrict__ K, float* __restrict__ V) {
    __shared__ float mrow[256];
    int k = blockIdx.x, b = blockIdx.y;
    int t = threadIdx.x;
    const float* mr = mem + ((size_t)b * 128 + k) * D_INN;
    mrow[t] = mr[t];
    mrow[t + 128] = mr[t + 128];
    __syncthreads();
    float aK = bk[t], aV = bv[t];
    for (int dd = 0; dd < D_INN; dd++) {
        float m = mrow[dd];
        aK += m * Wk[dd * D_MEMM + t];
        aV += m * Wv[dd * D_MEMM + t];
    }
    K[((size_t)b * 128 + k) * D_MEMM + t] = aK;
    V[((size_t)b * 128 + k) * D_MEMM + t] = aV;
}

// ---------------- Kernel 5: attention + epilogue ----------------
__global__ __launch_bounds__(256) void k_attn(const float* __restrict__ x,
        const float* __restrict__ proj, const float* __restrict__ y,
        const float* __restrict__ K, const float* __restrict__ V,
        const float* __restrict__ Wo, const float* __restrict__ bo,
        float* __restrict__ out) {
    __shared__ float q[128], sc[128], att[128];
    __shared__ float red[4];
    int l = blockIdx.x, b = blockIdx.y;
    size_t row = (size_t)b * LL + l;
    int t = threadIdx.x;
    if (t < 128) q[t] = proj[row * NTOT + NPROJ + t];
    __syncthreads();
    float scv = 0.f;
    if (t < 128) {
        const float* Kr = K + ((size_t)b * 128 + t) * D_MEMM;
        float a = 0.f;
        for (int m = 0; m < 128; m++) a += q[m] * Kr[m];
        scv = a * 0.125f;   // 1/sqrt(D_HIDDEN=64)
    }
    float v = (t < 128) ? scv : -3.4e38f;
    #pragma unroll
    for (int o = 1; o < 64; o <<= 1) v = fmaxf(v, __shfl_xor(v, o));
    if ((t & 63) == 0 && t < 128) red[t >> 6] = v;
    __syncthreads();
    float mx = fmaxf(red[0], red[1]);
    float ex = 0.f;
    if (t < 128) { ex = expf(scv - mx); sc[t] = ex; }
    float sv = (t < 128) ? ex : 0.f;
    #pragma unroll
    for (int o = 1; o < 64; o <<= 1) sv += __shfl_xor(sv, o);
    if ((t & 63) == 0 && t < 128) red[2 + (t >> 6)] = sv;
    __syncthreads();
    float denom = red[2] + red[3];
    if (t < 128) {
        const float* Vb = V + (size_t)b * 128 * D_MEMM;
        float a = 0.f;
        for (int k = 0; k < 128; k++) a += sc[k] * Vb[k * D_MEMM + t];
        att[t] = a / denom;
    }
    __syncthreads();
    float acc = bo[t];
    for (int m = 0; m < 128; m++) acc += att[m] * Wo[m * D_INN + t];
    float Ev = proj[row * NTOT + 192 + t];
    float Fv = proj[row * NTOT + 448 + t];
    out[row * D_INN + t] = y[row * D_INN + t] + acc * Ev + x[row * D_INN + t] * Fv;
}

extern "C" void kernel_launch(void* const* d_in, const int* in_sizes, int n_in,
                              void* d_out, int out_size, void* d_ws, size_t ws_size,
                              hipStream_t stream) {
    const float* x    = (const float*)d_in[0];
    const float* Wx   = (const float*)d_in[1];
    const float* Wdt  = (const float*)d_in[2];
    const float* bdt  = (const float*)d_in[3];
    const float* Wdtl = (const float*)d_in[4];
    const float* bdtl = (const float*)d_in[5];
    const float* A    = (const float*)d_in[6];
    const float* Dp   = (const float*)d_in[7];
    const float* Wq   = (const float*)d_in[8];
    const float* bq   = (const float*)d_in[9];
    const float* Wk   = (const float*)d_in[10];
    const float* bk   = (const float*)d_in[11];
    const float* Wv   = (const float*)d_in[12];
    const float* bv   = (const float*)d_in[13];
    const float* Wo   = (const float*)d_in[14];
    const float* bo   = (const float*)d_in[15];
    float* out = (float*)d_out;
    float* ws = (float*)d_ws;

    float* proj   = ws;                                    // 4096*864
    float* delta  = proj + (size_t)NROWS * NTOT;           // 4096*256
    float* deltal = delta + (size_t)NROWS * D_INN;         // 4096*256
    float* yb     = deltal + (size_t)NROWS * D_INN;        // 4096*256
    float* mem    = yb + (size_t)NROWS * D_INN;            // 2*128*256
    float* Kb     = mem + (size_t)BB * 128 * D_INN;        // 2*128*128
    float* Vb     = Kb + (size_t)BB * 128 * D_MEMM;        // 2*128*128

    hipLaunchKernelGGL(k_gemm, dim3(14, 64), dim3(256), 0, stream, x, Wx, Wq, bq, proj);
    hipLaunchKernelGGL(k_delta, dim3(NROWS), dim3(256), 0, stream,
                       proj, Wdt, bdt, Wdtl, bdtl, delta, deltal);
    hipLaunchKernelGGL(k_scan, dim3(64, 2, 2), dim3(256), 0, stream,
                       x, proj, A, Dp, delta, deltal, yb, mem);
    hipLaunchKernelGGL(k_kv, dim3(128, 2), dim3(128), 0, stream,
                       mem, Wk, bk, Wv, bv, Kb, Vb);
    hipLaunchKernelGGL(k_attn, dim3(LL, 2), dim3(256), 0, stream,
                       x, proj, yb, Kb, Vb, Wo, bo, out);
}

// Round 3
// 246.472 us; speedup vs baseline: 6.4165x; 1.6490x over previous
//
#include <hip/hip_runtime.h>
#include <math.h>

#define D_INN 256
#define D_HID 64
#define DTR 16
#define D_MEMM 128
#define BB 2
#define LL 2048
#define NROWS (BB*LL)   // 4096
#define NPROJ 736
#define NTOT 864        // 736 proj cols + 128 Q cols
#define SEG 8
#define SEGLEN (LL/SEG) // 256

// ---------------- Kernel 1: proj = x @ [W_xproj | W_Q] (+b_Q on Q cols) ----------------
__global__ __launch_bounds__(256) void k_gemm(const float* __restrict__ x,
        const float* __restrict__ Wx, const float* __restrict__ Wq,
        const float* __restrict__ bq, float* __restrict__ proj) {
    __shared__ float As[16][64];
    __shared__ float Bs[16][64];
    int tid = threadIdx.x;
    int tx = tid & 15, ty = tid >> 4;
    int row0 = blockIdx.y * 64;
    int col0 = blockIdx.x * 64;
    float acc[4][4] = {};
    for (int k0 = 0; k0 < D_INN; k0 += 16) {
        #pragma unroll
        for (int i = 0; i < 4; i++) {
            int idx = tid + i * 256;
            int kk = idx & 15, m = idx >> 4;
            As[kk][m] = x[(size_t)(row0 + m) * D_INN + k0 + kk];
        }
        #pragma unroll
        for (int i = 0; i < 4; i++) {
            int idx = tid + i * 256;
            int n = idx & 63, kk = idx >> 6;
            int col = col0 + n;
            float v = 0.f;
            if (col < NPROJ) v = Wx[(size_t)(k0 + kk) * NPROJ + col];
            else if (col < NTOT) v = Wq[(size_t)(k0 + kk) * D_MEMM + (col - NPROJ)];
            Bs[kk][n] = v;
        }
        __syncthreads();
        #pragma unroll
        for (int kk = 0; kk < 16; kk++) {
            float4 a4 = *(const float4*)&As[kk][ty * 4];
            float4 b4 = *(const float4*)&Bs[kk][tx * 4];
            float av[4] = {a4.x, a4.y, a4.z, a4.w};
            float bv[4] = {b4.x, b4.y, b4.z, b4.w};
            #pragma unroll
            for (int i = 0; i < 4; i++)
                #pragma unroll
                for (int j = 0; j < 4; j++)
                    acc[i][j] += av[i] * bv[j];
        }
        __syncthreads();
    }
    #pragma unroll
    for (int i = 0; i < 4; i++) {
        int row = row0 + ty * 4 + i;
        #pragma unroll
        for (int j = 0; j < 4; j++) {
            int col = col0 + tx * 4 + j;
            if (col < NTOT) {
                float v = acc[i][j];
                if (col >= NPROJ) v += bq[col - NPROJ];
                proj[(size_t)row * NTOT + col] = v;
            }
        }
    }
}

// ---------------- Kernel 2: delta / delta_l = softplus(dt @ W + b) ----------------
__global__ __launch_bounds__(256) void k_delta(const float* __restrict__ proj,
        const float* __restrict__ Wdt, const float* __restrict__ bdt,
        const float* __restrict__ Wdtl, const float* __restrict__ bdtl,
        float* __restrict__ delta, float* __restrict__ deltal) {
    __shared__ float sdt[16], sdtl[16];
    int row = blockIdx.x;
    int t = threadIdx.x;
    if (t < 16) sdt[t] = proj[(size_t)row * NTOT + 704 + t];
    else if (t < 32) sdtl[t - 16] = proj[(size_t)row * NTOT + 720 + (t - 16)];
    __syncthreads();
    float a1 = bdt[t], a2 = bdtl[t];
    #pragma unroll
    for (int r = 0; r < DTR; r++) {
        a1 += sdt[r] * Wdt[r * D_INN + t];
        a2 += sdtl[r] * Wdtl[r * D_INN + t];
    }
    delta[(size_t)row * D_INN + t]  = (a1 > 20.f) ? a1 : log1pf(expf(a1));
    deltal[(size_t)row * D_INN + t] = (a2 > 20.f) ? a2 : log1pf(expf(a2));
}

// ---------------- Kernel 3a: segmented scan pass 1 — per-segment (P, Q) ----------------
// grid (64 dtiles, 2 b, 16 = scan*8+seg); block 256 = 4 waves; wave w -> d = d0+w, lane = n.
// P = prod(exp2(delta*Aln)) = exp2(Aln * sum(delta)); Q = segment scan with s_in = 0.
__global__ __launch_bounds__(256) void k_scan1(const float* __restrict__ x,
        const float* __restrict__ proj, const float* __restrict__ A,
        const float* __restrict__ delta, const float* __restrict__ deltal,
        float* __restrict__ Pbuf, float* __restrict__ Qbuf) {
    __shared__ float Bs[2][16][64];
    __shared__ float dus[2][16][8];
    const int t = threadIdx.x;
    const int w = t >> 6, n = t & 63;
    const int b = blockIdx.y;
    const int scan = blockIdx.z >> 3, seg = blockIdx.z & 7;
    const int d0 = blockIdx.x * 4, d = d0 + w;
    const size_t rowbase = (size_t)b * LL + (size_t)seg * SEGLEN;
    const float* dsel = (scan == 0 ? delta : deltal);
    const int cB = (scan == 0) ? 0 : 64;
    const float Aln = A[d * D_HID + n] * 1.44269504f;
    const int lli = t >> 4, lc4 = (t & 15) * 4;

    float4 nB = {}, nDU = {};
    nB = *(const float4*)&proj[(rowbase + lli) * NTOT + cB + lc4];
    if (t < 16) nDU = *(const float4*)&dsel[(rowbase + t) * D_INN + d0];
    else if (t < 32) nDU = *(const float4*)&x[(rowbase + (t - 16)) * D_INN + d0];
    *(float4*)&Bs[0][lli][lc4] = nB;
    if (t < 16) *(float4*)&dus[0][t][0] = nDU;
    else if (t < 32) *(float4*)&dus[0][t - 16][4] = nDU;
    __syncthreads();

    float s = 0.f, sd = 0.f;
    for (int c = 0; c < SEGLEN / 16; ++c) {
        const int cur = c & 1;
        const bool hn = (c + 1 < SEGLEN / 16);
        if (hn) {
            size_t row = rowbase + (c + 1) * 16;
            nB = *(const float4*)&proj[(row + lli) * NTOT + cB + lc4];
            if (t < 16) nDU = *(const float4*)&dsel[(row + t) * D_INN + d0];
            else if (t < 32) nDU = *(const float4*)&x[(row + (t - 16)) * D_INN + d0];
        }
        #pragma unroll
        for (int li = 0; li < 16; ++li) {
            float dv = dus[cur][li][w];
            float uv = dus[cur][li][4 + w];
            float Bv = Bs[cur][li][n];
            float dA = exp2f(dv * Aln);
            s = fmaf(dA, s, (dv * uv) * Bv);
            sd += dv;
        }
        if (hn) {
            const int nxt = cur ^ 1;
            *(float4*)&Bs[nxt][lli][lc4] = nB;
            if (t < 16) *(float4*)&dus[nxt][t][0] = nDU;
            else if (t < 32) *(float4*)&dus[nxt][t - 16][4] = nDU;
        }
        __syncthreads();
    }
    size_t idx = ((((size_t)scan * 2 + b) * SEG + seg) * D_INN + d) * 64 + n;
    Pbuf[idx] = exp2f(sd * Aln);
    Qbuf[idx] = s;
}

// ---------------- Kernel 3b: segmented scan pass 2 — recompute with s_in, emit y / mem ----
__global__ __launch_bounds__(256) void k_scan2(const float* __restrict__ x,
        const float* __restrict__ proj, const float* __restrict__ A,
        const float* __restrict__ Dp, const float* __restrict__ delta,
        const float* __restrict__ deltal,
        const float* __restrict__ Pbuf, const float* __restrict__ Qbuf,
        float* __restrict__ y, float* __restrict__ mem) {
    __shared__ float Bs[2][8][64];
    __shared__ float Cs[2][8][64];
    __shared__ float dus[2][8][8];
    __shared__ float rbuf[4][8][65];
    const int t = threadIdx.x;
    const int w = t >> 6, n = t & 63;
    const int b = blockIdx.y;
    const int scan = blockIdx.z >> 3, seg = blockIdx.z & 7;
    const int d0 = blockIdx.x * 4, d = d0 + w;
    const size_t rowbase = (size_t)b * LL + (size_t)seg * SEGLEN;
    const float* dsel = (scan == 0 ? delta : deltal);
    const int cB = (scan == 0) ? 0 : 64;
    const float Aln = A[d * D_HID + n] * 1.44269504f;
    const float Dpv = Dp[d];
    const int lli = (t & 127) >> 4, lc4 = (t & 15) * 4;
    const bool isB = (t < 128);
    const int rli = n >> 3, g = n & 7;

    // s_in = prefix combine over earlier segments (<= 7 FMAs)
    float s = 0.f;
    {
        size_t base = (((size_t)scan * 2 + b) * SEG) * (D_INN * 64) + (size_t)d * 64 + n;
        for (int k = 0; k < seg; ++k) {
            float Pk = Pbuf[base + (size_t)k * (D_INN * 64)];
            float Qk = Qbuf[base + (size_t)k * (D_INN * 64)];
            s = fmaf(Pk, s, Qk);
        }
    }

    float4 nT = {}, nDU = {};
    {
        size_t row = rowbase + lli;
        if (isB) nT = *(const float4*)&proj[row * NTOT + cB + lc4];
        else if (scan == 0) nT = *(const float4*)&proj[row * NTOT + 128 + lc4];
        if (t < 8) nDU = *(const float4*)&dsel[(rowbase + t) * D_INN + d0];
        else if (t < 16) nDU = *(const float4*)&x[(rowbase + (t - 8)) * D_INN + d0];
    }
    if (isB) *(float4*)&Bs[0][lli][lc4] = nT;
    else if (scan == 0) *(float4*)&Cs[0][lli][lc4] = nT;
    if (t < 8) *(float4*)&dus[0][t][0] = nDU;
    else if (t < 16) *(float4*)&dus[0][t - 8][4] = nDU;
    __syncthreads();

    for (int c = 0; c < SEGLEN / 8; ++c) {   // 32 chunks of 8
        const int cur = c & 1;
        const bool hn = (c + 1 < SEGLEN / 8);
        if (hn) {
            size_t l0n = rowbase + (c + 1) * 8;
            if (isB) nT = *(const float4*)&proj[(l0n + lli) * NTOT + cB + lc4];
            else if (scan == 0) nT = *(const float4*)&proj[(l0n + lli) * NTOT + 128 + lc4];
            if (t < 8) nDU = *(const float4*)&dsel[(l0n + t) * D_INN + d0];
            else if (t < 16) nDU = *(const float4*)&x[(l0n + (t - 8)) * D_INN + d0];
        }
        float pv0 = 0.f;
        #pragma unroll
        for (int li = 0; li < 8; ++li) {
            float dv = dus[cur][li][w];
            float uv = dus[cur][li][4 + w];
            float Bv = Bs[cur][li][n];
            float dA = exp2f(dv * Aln);
            s = fmaf(dA, s, (dv * uv) * Bv);
            if (scan == 0) rbuf[w][li][n] = s * Cs[cur][li][n];
            else if (li == 0) pv0 = s;
        }
        if (scan == 0) {
            // same-wave reduce, no barrier needed: 8 lanes per row, 8 cols each
            float acc = 0.f;
            #pragma unroll
            for (int j = 0; j < 8; ++j) acc += rbuf[w][rli][g * 8 + j];
            acc += __shfl_xor(acc, 1);
            acc += __shfl_xor(acc, 2);
            acc += __shfl_xor(acc, 4);
            if (g == 0) {
                float xv = dus[cur][rli][4 + w];
                size_t row = rowbase + c * 8 + rli;
                y[row * D_INN + d] = acc + xv * Dpv;
            }
        } else if ((c & 1) == 0) {
            // memory takes l % 16 == 0 -> even chunks, li == 0
            float v = pv0;
            #pragma unroll
            for (int off = 32; off >= 1; off >>= 1) v += __shfl_xor(v, off);
            if (n == 0) {
                int kk = seg * 16 + (c >> 1);
                mem[((size_t)b * 128 + kk) * D_INN + d] = v;
            }
        }
        if (hn) {
            const int nxt = cur ^ 1;
            if (isB) *(float4*)&Bs[nxt][lli][lc4] = nT;
            else if (scan == 0) *(float4*)&Cs[nxt][lli][lc4] = nT;
            if (t < 8) *(float4*)&dus[nxt][t][0] = nDU;
            else if (t < 16) *(float4*)&dus[nxt][t - 8][4] = nDU;
        }
        __syncthreads();
    }
}

// ---------------- Kernel 4: K, V = memory @ W_K/V + b ----------------
__global__ __launch_bounds__(128) void k_kv(const float* __restrict__ mem,
        const float* __restrict__ Wk, const float* __restrict__ bk,
        const float* __restrict__ Wv, const float* __restrict__ bv,
        float* __restrict__ K, float* __restrict__ V) {
    __shared__ float mrow[256];
    int k = blockIdx.x, b = blockIdx.y;
    int t = threadIdx.x;
    const float* mr = mem + ((size_t)b * 128 + k) * D_INN;
    mrow[t] = mr[t];
    mrow[t + 128] = mr[t + 128];
    __syncthreads();
    float aK = bk[t], aV = bv[t];
    for (int dd = 0; dd < D_INN; dd++) {
        float m = mrow[dd];
        aK += m * Wk[dd * D_MEMM + t];
        aV += m * Wv[dd * D_MEMM + t];
    }
    K[((size_t)b * 128 + k) * D_MEMM + t] = aK;
    V[((size_t)b * 128 + k) * D_MEMM + t] = aV;
}

// ---------------- Kernel 5: attention + epilogue ----------------
__global__ __launch_bounds__(256) void k_attn(const float* __restrict__ x,
        const float* __restrict__ proj, const float* __restrict__ y,
        const float* __restrict__ K, const float* __restrict__ V,
        const float* __restrict__ Wo, const float* __restrict__ bo,
        float* __restrict__ out) {
    __shared__ float q[128], sc[128], att[128];
    __shared__ float red[4];
    int l = blockIdx.x, b = blockIdx.y;
    size_t row = (size_t)b * LL + l;
    int t = threadIdx.x;
    if (t < 128) q[t] = proj[row * NTOT + NPROJ + t];
    __syncthreads();
    float scv = 0.f;
    if (t < 128) {
        const float* Kr = K + ((size_t)b * 128 + t) * D_MEMM;
        float a = 0.f;
        for (int m = 0; m < 128; m++) a += q[m] * Kr[m];
        scv = a * 0.125f;   // 1/sqrt(D_HIDDEN=64)
    }
    float v = (t < 128) ? scv : -3.4e38f;
    #pragma unroll
    for (int o = 1; o < 64; o <<= 1) v = fmaxf(v, __shfl_xor(v, o));
    if ((t & 63) == 0 && t < 128) red[t >> 6] = v;
    __syncthreads();
    float mx = fmaxf(red[0], red[1]);
    float ex = 0.f;
    if (t < 128) { ex = expf(scv - mx); sc[t] = ex; }
    float sv = (t < 128) ? ex : 0.f;
    #pragma unroll
    for (int o = 1; o < 64; o <<= 1) sv += __shfl_xor(sv, o);
    if ((t & 63) == 0 && t < 128) red[2 + (t >> 6)] = sv;
    __syncthreads();
    float denom = red[2] + red[3];
    if (t < 128) {
        const float* Vb = V + (size_t)b * 128 * D_MEMM;
        float a = 0.f;
        for (int k = 0; k < 128; k++) a += sc[k] * Vb[k * D_MEMM + t];
        att[t] = a / denom;
    }
    __syncthreads();
    float acc = bo[t];
    for (int m = 0; m < 128; m++) acc += att[m] * Wo[m * D_INN + t];
    float Ev = proj[row * NTOT + 192 + t];
    float Fv = proj[row * NTOT + 448 + t];
    out[row * D_INN + t] = y[row * D_INN + t] + acc * Ev + x[row * D_INN + t] * Fv;
}

extern "C" void kernel_launch(void* const* d_in, const int* in_sizes, int n_in,
                              void* d_out, int out_size, void* d_ws, size_t ws_size,
                              hipStream_t stream) {
    const float* x    = (const float*)d_in[0];
    const float* Wx   = (const float*)d_in[1];
    const float* Wdt  = (const float*)d_in[2];
    const float* bdt  = (const float*)d_in[3];
    const float* Wdtl = (const float*)d_in[4];
    const float* bdtl = (const float*)d_in[5];
    const float* A    = (const float*)d_in[6];
    const float* Dp   = (const float*)d_in[7];
    const float* Wq   = (const float*)d_in[8];
    const float* bq   = (const float*)d_in[9];
    const float* Wk   = (const float*)d_in[10];
    const float* bk   = (const float*)d_in[11];
    const float* Wv   = (const float*)d_in[12];
    const float* bv   = (const float*)d_in[13];
    const float* Wo   = (const float*)d_in[14];
    const float* bo   = (const float*)d_in[15];
    float* out = (float*)d_out;
    float* ws = (float*)d_ws;

    float* proj   = ws;                                    // 4096*864
    float* delta  = proj + (size_t)NROWS * NTOT;           // 4096*256
    float* deltal = delta + (size_t)NROWS * D_INN;         // 4096*256
    float* yb     = deltal + (size_t)NROWS * D_INN;        // 4096*256
    float* mem    = yb + (size_t)NROWS * D_INN;            // 2*128*256
    float* Kb     = mem + (size_t)BB * 128 * D_INN;        // 2*128*128
    float* Vb     = Kb + (size_t)BB * 128 * D_MEMM;        // 2*128*128
    float* Pbuf   = Vb + (size_t)BB * 128 * D_MEMM;        // 2*2*8*256*64 = 2M floats
    float* Qbuf   = Pbuf + (size_t)4 * SEG * D_INN * 64;   // 2M floats

    hipLaunchKernelGGL(k_gemm, dim3(14, 64), dim3(256), 0, stream, x, Wx, Wq, bq, proj);
    hipLaunchKernelGGL(k_delta, dim3(NROWS), dim3(256), 0, stream,
                       proj, Wdt, bdt, Wdtl, bdtl, delta, deltal);
    hipLaunchKernelGGL(k_scan1, dim3(64, 2, 16), dim3(256), 0, stream,
                       x, proj, A, delta, deltal, Pbuf, Qbuf);
    hipLaunchKernelGGL(k_scan2, dim3(64, 2, 16), dim3(256), 0, stream,
                       x, proj, A, Dp, delta, deltal, Pbuf, Qbuf, yb, mem);
    hipLaunchKernelGGL(k_kv, dim3(128, 2), dim3(128), 0, stream,
                       mem, Wk, bk, Wv, bv, Kb, Vb);
    hipLaunchKernelGGL(k_attn, dim3(LL, 2), dim3(256), 0, stream,
                       x, proj, yb, Kb, Vb, Wo, bo, out);
}